// Round 15
// baseline (1184.341 us; speedup 1.0000x reference)
//
#include <hip/hip_runtime.h>
#include <hip/hip_bf16.h>
#include <math.h>

#define BATCH 128
#define TT    12
#define CIN   10
#define HID   64
#define PLANE 625
#define NU    10          // 16B channel-units per pixel (80 padded ch)
#define IPB   50000       // shorts per batch image in inp: NU*PLANE*8
#define NKB   45          // k-blocks: 9 taps * 5 chunks of 16 ch
#define NKB_ALLOC (NKB+6) // slack frags so tail prefetch stays in-bounds
#define CSZ   (BATCH*PLANE*HID)   // floats in c buffer
#define KSPLIT 10         // k_mlp1 k splits

typedef __attribute__((ext_vector_type(8)))  short bf16x8;
typedef __attribute__((ext_vector_type(16))) float f32x16;

__device__ __forceinline__ float fsigm(float v){ return 1.f/(1.f+__expf(-v)); }
__device__ __forceinline__ float ftanh(float v){ return 1.f - 2.f/(__expf(2.f*v)+1.f); }
__device__ __forceinline__ unsigned short f2bf(float v){
    __hip_bfloat16 b = __float2bfloat16(v);
    return *reinterpret_cast<unsigned short*>(&b);
}

// ---- prepack conv_w (256,74,3,3) f32 -> B-fragments bf16 ----
// k = tap*80 + ch, n-permutation: col = jlo*4 + g  (j = nt*8+jlo, o = g*64+j)
// frag layout (32x32x16 B): lane l: col = l&31, k_local = (l>>5)*8 + e
__global__ void k_wprep(const float* __restrict__ w, unsigned short* __restrict__ wpk){
    int tid = blockIdx.x*256 + threadIdx.x;      // NKB*8*64 = 23040 total
    if (tid >= NKB*8*64) return;
    int lane = tid & 63;
    int nt   = (tid >> 6) & 7;
    int kb   = tid >> 9;
    int tap = kb/5, ci = kb - tap*5;
    int ky = tap/3, kx = tap - ky*3;
    int g = lane & 3, jlo = (lane & 31) >> 2, kh = lane >> 5;
    int o = g*64 + nt*8 + jlo;
    union { unsigned short u[8]; float4 f; } pk;
    #pragma unroll
    for (int e = 0; e < 8; ++e){
        int ch = ci*16 + kh*8 + e;
        float v = (ch < 74) ? w[((o*74 + ch)*3 + ky)*3 + kx] : 0.f;
        pk.u[e] = f2bf(v);
    }
    *reinterpret_cast<float4*>(wpk + (size_t)tid*8) = pk.f;   // idx = (kb*8+nt)*64+lane
}

// ---- transpose w1 -> w1t rows k' = m*64+j ----
__global__ void k_w1prep(const float* __restrict__ w1, float* __restrict__ w1t){
    int tid = blockIdx.x*256 + threadIdx.x;
    if (tid >= 40000*4) return;
    int rowp = tid >> 2, f4 = tid & 3;
    int m = rowp >> 6, j = rowp & 63;
    const float4* src = (const float4*)(w1 + (size_t)(j*625 + m)*16);
    ((float4*)(w1t + (size_t)rowp*16))[f4] = src[f4];
}

// ---- copy x_0 into inp buffer x-slots (unit-major bf16 layout) ----
__global__ void k_xcopy(const float* __restrict__ x, unsigned short* __restrict__ inp, int t){
    int idx = blockIdx.x*256 + threadIdx.x;
    if (idx >= BATCH*CIN*PLANE) return;
    int m  = idx % PLANE;
    int r  = idx / PLANE;
    int ch = r % CIN;
    int b  = r / CIN;
    float v = x[((size_t)(b*TT + t)*CIN + ch)*PLANE + m];
    inp[(size_t)b*IPB + ((((ch>>3)*PLANE) + m)<<3) + (ch&7)] = f2bf(v);
}

// ---- fused conv-as-GEMM (MFMA bf16) + LSTM pointwise + next-step x-copy ----
// 128m x 256n blocks, grid (5 mg, 128 b) = 640 blocks, 4 waves of 4mt x 2nt.
// Round-14 post-mortem: per-wave amortization beats occupancy (R7 4mt@49us >
// R8 2mt@57us > R14 barriers@66us). This config halves A-LDS reads per block
// vs R7 (the largest resource term, 18us/CU) and doubles MFMA per A-read,
// while keeping barrier-free global B (1-deep rotation, R7-style).
// acc = 8 x f32x16 = 128 VGPR; ~210 total -> 2 waves/SIMD; per-wave ILP
// (8 independent MFMA chains) covers the low occupancy.
__global__ __launch_bounds__(256) void k_gemm(
    const float* __restrict__ x,
    const unsigned short* __restrict__ inp,   // step-t input, unit-major
    unsigned short* __restrict__ inpn,        // next-step buffer
    const unsigned short* __restrict__ wpk,
    const float* __restrict__ bias,           // conv_b[256], o = g*64+j
    float* __restrict__ cbuf,                 // [b][625][64] fp32
    unsigned short* __restrict__ hbf,         // [b][m*64+j] relu'd bf16 h (t=TT-1)
    int t)
{
    __shared__ __align__(16) unsigned short at2[2160*8];   // [10 u][8r*27c][8], 34.56 KB

    const int tid  = threadIdx.x;
    const int mg   = blockIdx.x;              // 0..4 (128 m each; m 625..639 pad)
    const int b    = blockIdx.y;
    const int lane = tid & 63;
    const int ntp  = tid >> 6;                // wave id = n-tile pair (nt = 2*ntp, 2*ntp+1)
    const int nt0  = ntp*2;
    const int r0row = (mg*128)/25;            // 0,5,10,15,20

    // ---- stage A-tile: rows r0row-1..r0row+6, cols -1..25, zero halo/pad ----
    const unsigned short* ib = inp + (size_t)b*IPB;
    for (int idx = tid; idx < 2160; idx += 256){
        int q   = idx/216, pix = idx - q*216;
        int rr  = pix/27,  cc  = pix - rr*27;
        int gr  = r0row - 1 + rr, gc = cc - 1;
        float4 v = {0.f,0.f,0.f,0.f};
        if ((unsigned)gr < 25u && (unsigned)gc < 25u)
            v = *reinterpret_cast<const float4*>(ib + (((size_t)q*PLANE + gr*25 + gc)<<3));
        *reinterpret_cast<float4*>(at2 + ((size_t)idx<<3)) = v;
    }

    // per-lane A bases for the wave's 4 m-tiles (rebased so all tap offsets >= 0)
    const int kh = lane >> 5;
    const unsigned short *p0, *p1, *p2, *p3;
    {
        int m0 = mg*128 + 0*32 + (lane & 31), r_ = m0/25, c_ = m0 - r_*25;
        p0 = at2 + kh*1728 + (((r_ - r0row + 1)*27 + c_ - 27) << 3);
        int m1 = mg*128 + 1*32 + (lane & 31); r_ = m1/25; c_ = m1 - r_*25;
        p1 = at2 + kh*1728 + (((r_ - r0row + 1)*27 + c_ - 27) << 3);
        int m2 = mg*128 + 2*32 + (lane & 31); r_ = m2/25; c_ = m2 - r_*25;
        p2 = at2 + kh*1728 + (((r_ - r0row + 1)*27 + c_ - 27) << 3);
        int m3 = mg*128 + 3*32 + (lane & 31); r_ = m3/25; c_ = m3 - r_*25;
        p3 = at2 + kh*1728 + (((r_ - r0row + 1)*27 + c_ - 27) << 3);
    }

    f32x16 acc[4][2];                          // [mt][nt-in-pair]
    #pragma unroll
    for (int mt = 0; mt < 4; ++mt)
        #pragma unroll
        for (int n = 0; n < 2; ++n)
            #pragma unroll
            for (int e = 0; e < 16; ++e) acc[mt][n][e] = 0.f;

    __syncthreads();

    // ---- K loop: 9 taps x 5 ci; A & B 1-deep rotated, all ds offsets immediate ----
    const bf16x8* wf = reinterpret_cast<const bf16x8*>(wpk) + nt0*64 + lane;
    bf16x8 Bc0 = wf[0], Bc1 = wf[64];
    bf16x8 fc0 = *reinterpret_cast<const bf16x8*>(p0);
    bf16x8 fc1 = *reinterpret_cast<const bf16x8*>(p1);
    bf16x8 fc2 = *reinterpret_cast<const bf16x8*>(p2);
    bf16x8 fc3 = *reinterpret_cast<const bf16x8*>(p3);

    #pragma unroll 1
    for (int tap = 0; tap < 9; ++tap){
        const int d = (tap == 2 || tap == 5) ? 25*8 : 8;   // pixel-walk delta (shorts)
        const unsigned short* q0 = (tap < 8) ? p0 + d : p0;  // tap-8 prefetch guarded:
        const unsigned short* q1 = (tap < 8) ? p1 + d : p1;  // re-reads current (unused)
        const unsigned short* q2 = (tap < 8) ? p2 + d : p2;
        const unsigned short* q3 = (tap < 8) ? p3 + d : p3;
        const bf16x8* wnx = wf + 2560;          // next tap's frags (slack past NKB)

        #pragma unroll
        for (int ci = 0; ci < 5; ++ci){
            bf16x8 nB0 = (ci < 4) ? wf[(ci+1)*512]      : wnx[0];
            bf16x8 nB1 = (ci < 4) ? wf[(ci+1)*512 + 64] : wnx[64];
            bf16x8 t0 = *reinterpret_cast<const bf16x8*>((ci < 4) ? p0 + (ci+1)*3456 : q0);
            bf16x8 t1 = *reinterpret_cast<const bf16x8*>((ci < 4) ? p1 + (ci+1)*3456 : q1);
            bf16x8 t2 = *reinterpret_cast<const bf16x8*>((ci < 4) ? p2 + (ci+1)*3456 : q2);
            bf16x8 t3 = *reinterpret_cast<const bf16x8*>((ci < 4) ? p3 + (ci+1)*3456 : q3);
            acc[0][0] = __builtin_amdgcn_mfma_f32_32x32x16_bf16(fc0, Bc0, acc[0][0], 0,0,0);
            acc[0][1] = __builtin_amdgcn_mfma_f32_32x32x16_bf16(fc0, Bc1, acc[0][1], 0,0,0);
            acc[1][0] = __builtin_amdgcn_mfma_f32_32x32x16_bf16(fc1, Bc0, acc[1][0], 0,0,0);
            acc[1][1] = __builtin_amdgcn_mfma_f32_32x32x16_bf16(fc1, Bc1, acc[1][1], 0,0,0);
            acc[2][0] = __builtin_amdgcn_mfma_f32_32x32x16_bf16(fc2, Bc0, acc[2][0], 0,0,0);
            acc[2][1] = __builtin_amdgcn_mfma_f32_32x32x16_bf16(fc2, Bc1, acc[2][1], 0,0,0);
            acc[3][0] = __builtin_amdgcn_mfma_f32_32x32x16_bf16(fc3, Bc0, acc[3][0], 0,0,0);
            acc[3][1] = __builtin_amdgcn_mfma_f32_32x32x16_bf16(fc3, Bc1, acc[3][1], 0,0,0);
            Bc0 = nB0; Bc1 = nB1; fc0 = t0; fc1 = t1; fc2 = t2; fc3 = t3;
        }
        wf = wnx; p0 = q0; p1 = q1; p2 = q2; p3 = q3;
    }

    // ---- fused LSTM epilogue: quad transpose -> all lanes update ----
    const int g   = lane & 3;
    const int jlo = (lane & 31) >> 2;
    const int j0  = (nt0+0)*8 + jlo;
    const int j1  = (nt0+1)*8 + jlo;
    const float bown0 = bias[g*64 + j0];
    const float bown1 = bias[g*64 + j1];
    const float sA = (g == 3) ? 2.f : 1.f;    // act = sA*sigm(sA*x) + sB (tanh when g=3)
    const float sB = (g == 3) ? -1.f : 0.f;
    const int  mbase = mg*128 + 4*kh;
    const bool gb0 = (g & 1), gb1 = (g & 2);
    float* cb = cbuf + (size_t)b*PLANE*HID;
    unsigned short* hn  = inpn + (size_t)b*IPB;
    unsigned short* hfb = hbf  + (size_t)b*40000;

    #pragma unroll
    for (int mt = 0; mt < 4; ++mt){
        #pragma unroll
        for (int n = 0; n < 2; ++n){
            const int   jj = n ? j1 : j0;
            const float bw = n ? bown1 : bown0;
            const int  chh = CIN + jj, uh = chh >> 3, sh = chh & 7;
            #pragma unroll
            for (int rq = 0; rq < 4; ++rq){
                float v0 = fmaf(sA, fsigm(sA*(acc[mt][n][rq*4+0] + bw)), sB);
                float v1 = fmaf(sA, fsigm(sA*(acc[mt][n][rq*4+1] + bw)), sB);
                float v2 = fmaf(sA, fsigm(sA*(acc[mt][n][rq*4+2] + bw)), sB);
                float v3 = fmaf(sA, fsigm(sA*(acc[mt][n][rq*4+3] + bw)), sB);
                float s;
                s = __shfl_xor(gb0 ? v0 : v1, 1); if (gb0) v0 = s; else v1 = s;
                s = __shfl_xor(gb0 ? v2 : v3, 1); if (gb0) v2 = s; else v3 = s;
                s = __shfl_xor(gb1 ? v0 : v2, 2); if (gb1) v0 = s; else v2 = s;
                s = __shfl_xor(gb1 ? v1 : v3, 2); if (gb1) v1 = s; else v3 = s;
                // v0=i, v1=f, v2=o, v3=g~ of element m
                const int m = mbase + mt*32 + g + 8*rq;
                if (m < PLANE){
                    float co = cb[m*HID + jj];
                    float cn = fmaf(v1, co, v0*v3);
                    float h  = v2 * ftanh(cn);
                    if (t < TT-1){
                        cb[m*HID + jj] = cn;
                        hn[((uh*PLANE + m) << 3) + sh] = f2bf(h);
                    } else {
                        hfb[m*64 + jj] = f2bf(h > 0.f ? h : 0.f);
                    }
                }
            }
        }
    }

    // ---- fused x-copy for step t+1 (this block's 128-m slice) ----
    if (t < TT-1){
        const float* xn = x + (size_t)(b*TT + t + 1)*CIN*PLANE;
        for (int idx = tid; idx < 1280; idx += 256){
            int ch = idx >> 7, mi = idx & 127;
            int m = mg*128 + mi;
            if (m < PLANE)
                inpn[(size_t)b*IPB + ((((ch>>3)*PLANE) + m)<<3) + (ch&7)] =
                    f2bf(xn[ch*PLANE + m]);
        }
    }
}

// -------- MLP stage 1: partial h@w1, coalesced bf16 h + transposed w1 --------
__global__ __launch_bounds__(256) void k_mlp1(
    const unsigned short* __restrict__ hbf, const float* __restrict__ w1t,
    float* __restrict__ part)
{
    __shared__ float xw[4][4][16];
    const int ks = blockIdx.x, bg = blockIdx.y, tid = threadIdx.x;
    const int kw0 = ks*4000, kw1 = kw0 + 4000;
    const unsigned short* h0 = hbf + (size_t)(bg*4+0)*40000;
    const unsigned short* h1 = hbf + (size_t)(bg*4+1)*40000;
    const unsigned short* h2 = hbf + (size_t)(bg*4+2)*40000;
    const unsigned short* h3 = hbf + (size_t)(bg*4+3)*40000;

    float acc[4][16];
    #pragma unroll
    for (int bi = 0; bi < 4; ++bi)
        #pragma unroll
        for (int n = 0; n < 16; ++n) acc[bi][n] = 0.f;

    for (int kw = kw0 + tid*2; kw < kw1; kw += 512){
        const float4* wp = (const float4*)(w1t + (size_t)kw*16);
        float4 q0 = wp[0], q1 = wp[1], q2 = wp[2], q3 = wp[3];
        float4 r0 = wp[4], r1 = wp[5], r2 = wp[6], r3 = wp[7];
        unsigned int u0 = *(const unsigned int*)(h0 + kw);
        unsigned int u1 = *(const unsigned int*)(h1 + kw);
        unsigned int u2 = *(const unsigned int*)(h2 + kw);
        unsigned int u3 = *(const unsigned int*)(h3 + kw);
        #define ACC1(bi, u) { \
            float fl = __uint_as_float((u) << 16); \
            float fh = __uint_as_float((u) & 0xffff0000u); \
            acc[bi][ 0]=fmaf(fl,q0.x,fmaf(fh,r0.x,acc[bi][ 0])); \
            acc[bi][ 1]=fmaf(fl,q0.y,fmaf(fh,r0.y,acc[bi][ 1])); \
            acc[bi][ 2]=fmaf(fl,q0.z,fmaf(fh,r0.z,acc[bi][ 2])); \
            acc[bi][ 3]=fmaf(fl,q0.w,fmaf(fh,r0.w,acc[bi][ 3])); \
            acc[bi][ 4]=fmaf(fl,q1.x,fmaf(fh,r1.x,acc[bi][ 4])); \
            acc[bi][ 5]=fmaf(fl,q1.y,fmaf(fh,r1.y,acc[bi][ 5])); \
            acc[bi][ 6]=fmaf(fl,q1.z,fmaf(fh,r1.z,acc[bi][ 6])); \
            acc[bi][ 7]=fmaf(fl,q1.w,fmaf(fh,r1.w,acc[bi][ 7])); \
            acc[bi][ 8]=fmaf(fl,q2.x,fmaf(fh,r2.x,acc[bi][ 8])); \
            acc[bi][ 9]=fmaf(fl,q2.y,fmaf(fh,r2.y,acc[bi][ 9])); \
            acc[bi][10]=fmaf(fl,q2.z,fmaf(fh,r2.z,acc[bi][10])); \
            acc[bi][11]=fmaf(fl,q2.w,fmaf(fh,r2.w,acc[bi][11])); \
            acc[bi][12]=fmaf(fl,q3.x,fmaf(fh,r3.x,acc[bi][12])); \
            acc[bi][13]=fmaf(fl,q3.y,fmaf(fh,r3.y,acc[bi][13])); \
            acc[bi][14]=fmaf(fl,q3.z,fmaf(fh,r3.z,acc[bi][14])); \
            acc[bi][15]=fmaf(fl,q3.w,fmaf(fh,r3.w,acc[bi][15])); }
        ACC1(0, u0) ACC1(1, u1) ACC1(2, u2) ACC1(3, u3)
        #undef ACC1
    }

    #pragma unroll
    for (int d = 1; d < 64; d <<= 1)
        #pragma unroll
        for (int bi = 0; bi < 4; ++bi)
            #pragma unroll
            for (int n = 0; n < 16; ++n) acc[bi][n] += __shfl_xor(acc[bi][n], d);
    if ((tid & 63) == 0){
        int w = tid >> 6;
        #pragma unroll
        for (int bi = 0; bi < 4; ++bi)
            #pragma unroll
            for (int n = 0; n < 16; ++n) xw[w][bi][n] = acc[bi][n];
    }
    __syncthreads();
    if (tid < 64){
        int bi = tid >> 4, n = tid & 15;
        float s = xw[0][bi][n] + xw[1][bi][n] + xw[2][bi][n] + xw[3][bi][n];
        part[((size_t)(bg*4 + bi)*KSPLIT + ks)*16 + n] = s;
    }
}

// -------- MLP stage 2: fold partials, 16 -> 8 -> 2 -> log_softmax --------
__global__ __launch_bounds__(128) void k_mlp2(
    const float* __restrict__ part,
    const float* __restrict__ b1,
    const float* __restrict__ w2, const float* __restrict__ b2,
    const float* __restrict__ w3, const float* __restrict__ b3,
    float* __restrict__ out)
{
    const int b = threadIdx.x;
    float h1[16];
    #pragma unroll
    for (int i = 0; i < 16; ++i) h1[i] = b1[i];
    for (int s = 0; s < KSPLIT; ++s)
        #pragma unroll
        for (int i = 0; i < 16; ++i) h1[i] += part[((size_t)b * KSPLIT + s) * 16 + i];
    #pragma unroll
    for (int i = 0; i < 16; ++i) h1[i] = h1[i] > 0.f ? h1[i] : 0.f;

    float h2[8];
    #pragma unroll
    for (int i = 0; i < 8; ++i){
        float s2 = b2[i];
        #pragma unroll
        for (int k2 = 0; k2 < 16; ++k2) s2 += h1[k2] * w2[k2*8 + i];
        h2[i] = s2 > 0.f ? s2 : 0.f;
    }
    float l0 = b3[0], l1 = b3[1];
    #pragma unroll
    for (int k3 = 0; k3 < 8; ++k3){ l0 += h2[k3]*w3[k3*2]; l1 += h2[k3]*w3[k3*2+1]; }
    float m   = fmaxf(l0, l1);
    float lse = m + logf(__expf(l0 - m) + __expf(l1 - m));
    out[b*2 + 0] = l0 - lse;
    out[b*2 + 1] = l1 - lse;
}

extern "C" void kernel_launch(void* const* d_in, const int* in_sizes, int n_in,
                              void* d_out, int out_size, void* d_ws, size_t ws_size,
                              hipStream_t stream) {
    const float* x      = (const float*)d_in[0];
    const float* conv_w = (const float*)d_in[1];
    const float* conv_b = (const float*)d_in[2];
    const float* w1     = (const float*)d_in[3];
    const float* b1     = (const float*)d_in[4];
    const float* w2     = (const float*)d_in[5];
    const float* b2     = (const float*)d_in[6];
    const float* w3     = (const float*)d_in[7];
    const float* b3     = (const float*)d_in[8];
    float* out = (float*)d_out;

    unsigned short* inp0 = (unsigned short*)d_ws;
    unsigned short* inp1 = inp0 + (size_t)BATCH*IPB;
    float* c   = (float*)(inp1 + (size_t)BATCH*IPB);
    unsigned short* hbf = (unsigned short*)(c + CSZ);
    unsigned short* wpk = hbf + (size_t)BATCH*40000;
    float* w1t  = (float*)(wpk + (size_t)NKB_ALLOC*8*64*8);
    float* part = w1t + 640000;

    // ws poisoned 0xAA, not re-poisoned between replays -> re-init every call
    hipMemsetAsync(inp0, 0, (size_t)BATCH*IPB*2, stream);   // zeros h(t=0) + ch pad
    hipMemsetAsync(inp1, 0, (size_t)BATCH*IPB*2, stream);   // zeros ch pad
    hipMemsetAsync(c,    0, (size_t)CSZ*4,       stream);

    k_wprep <<<dim3(90),   dim3(256), 0, stream>>>(conv_w, wpk);
    k_w1prep<<<dim3(625),  dim3(256), 0, stream>>>(w1, w1t);
    k_xcopy <<<dim3(3125), dim3(256), 0, stream>>>(x, inp0, 0);

    for (int t = 0; t < TT; ++t){
        unsigned short* ic  = (t & 1) ? inp1 : inp0;
        unsigned short* in_ = (t & 1) ? inp0 : inp1;
        k_gemm<<<dim3(5, BATCH), dim3(256), 0, stream>>>(x, ic, in_, wpk, conv_b, c, hbf, t);
    }
    k_mlp1<<<dim3(KSPLIT, 32), dim3(256), 0, stream>>>(hbf, w1t, part);
    k_mlp2<<<dim3(1), dim3(128), 0, stream>>>(part, b1, w2, b2, w3, b3, out);
}

// Round 16
// 617.104 us; speedup vs baseline: 1.9192x; 1.9192x over previous
//
#include <hip/hip_runtime.h>
#include <hip/hip_bf16.h>
#include <math.h>

#define BATCH 128
#define TT    12
#define CIN   10
#define HID   64
#define PLANE 625
#define NU    10          // 16B channel-units per pixel (80 padded ch)
#define IPB   50000       // shorts per batch image in inp: NU*PLANE*8
#define NKB   45          // k-blocks: 9 taps * 5 chunks of 16 ch
#define NKB_ALLOC (NKB+6)
#define CSZ   (BATCH*PLANE*HID)   // floats in c buffer
#define KSPLIT 10         // k_mlp1 k splits

typedef __attribute__((ext_vector_type(8)))  short bf16x8;
typedef __attribute__((ext_vector_type(16))) float f32x16;

__device__ __forceinline__ float fsigm(float v){ return 1.f/(1.f+__expf(-v)); }
__device__ __forceinline__ float ftanh(float v){ return 1.f - 2.f/(__expf(2.f*v)+1.f); }
__device__ __forceinline__ unsigned short f2bf(float v){
    __hip_bfloat16 b = __float2bfloat16(v);
    return *reinterpret_cast<unsigned short*>(&b);
}

// ---- prepack conv_w (256,74,3,3) f32 -> B-fragments bf16 ----
// k = tap*80 + ch, n-permutation: col = jlo*4 + g  (j = nt*8+jlo, o = g*64+j)
// frag layout (32x32x16 B): lane l: col = l&31, k_local = (l>>5)*8 + e
__global__ void k_wprep(const float* __restrict__ w, unsigned short* __restrict__ wpk){
    int tid = blockIdx.x*256 + threadIdx.x;      // NKB*8*64 = 23040 total
    if (tid >= NKB*8*64) return;
    int lane = tid & 63;
    int nt   = (tid >> 6) & 7;
    int kb   = tid >> 9;
    int tap = kb/5, ci = kb - tap*5;
    int ky = tap/3, kx = tap - ky*3;
    int g = lane & 3, jlo = (lane & 31) >> 2, kh = lane >> 5;
    int o = g*64 + nt*8 + jlo;
    union { unsigned short u[8]; float4 f; } pk;
    #pragma unroll
    for (int e = 0; e < 8; ++e){
        int ch = ci*16 + kh*8 + e;
        float v = (ch < 74) ? w[((o*74 + ch)*3 + ky)*3 + kx] : 0.f;
        pk.u[e] = f2bf(v);
    }
    *reinterpret_cast<float4*>(wpk + (size_t)tid*8) = pk.f;   // idx = (kb*8+nt)*64+lane
}

// ---- transpose w1 -> w1t rows k' = m*64+j ----
__global__ void k_w1prep(const float* __restrict__ w1, float* __restrict__ w1t){
    int tid = blockIdx.x*256 + threadIdx.x;
    if (tid >= 40000*4) return;
    int rowp = tid >> 2, f4 = tid & 3;
    int m = rowp >> 6, j = rowp & 63;
    const float4* src = (const float4*)(w1 + (size_t)(j*625 + m)*16);
    ((float4*)(w1t + (size_t)rowp*16))[f4] = src[f4];
}

// ---- copy x_0 into inp buffer x-slots (unit-major bf16 layout) ----
__global__ void k_xcopy(const float* __restrict__ x, unsigned short* __restrict__ inp, int t){
    int idx = blockIdx.x*256 + threadIdx.x;
    if (idx >= BATCH*CIN*PLANE) return;
    int m  = idx % PLANE;
    int r  = idx / PLANE;
    int ch = r % CIN;
    int b  = r / CIN;
    float v = x[((size_t)(b*TT + t)*CIN + ch)*PLANE + m];
    inp[(size_t)b*IPB + ((((ch>>3)*PLANE) + m)<<3) + (ch&7)] = f2bf(v);
}

// per-kb A offset in shorts (64m tile): tap = kb/5, ci = kb%5;
// AOFF = (ky*27 + kx)*8 + ci*2592  — compile-time immediate after full unroll
#define AOFF(kb) (((((kb)/5)/3)*27 + (((kb)/5)%3))*8 + ((kb)%5)*2592)

// ---- fused conv-as-GEMM (MFMA bf16) + LSTM pointwise + next-step x-copy ----
// R8 structure (64m x 256n, grid (10,128), 8 waves of 2mt x 1nt, barrier-free global B)
// + ONE lever: fully-unrolled 45-step K-loop with modulo register rotation,
// A prefetched 3 kb deep (LDS ~120cyc latency; 1-deep gave only ~35cyc cover — the
// R12/R13-invariant lgkmcnt stall), B 4 kb deep (L2 ~200cyc). Rotation slots bound
// compiler hoisting via WAR; all indices compile-time (no scratch).
__global__ __launch_bounds__(512) void k_gemm(
    const float* __restrict__ x,
    const unsigned short* __restrict__ inp,   // step-t input, unit-major
    unsigned short* __restrict__ inpn,        // next-step buffer
    const unsigned short* __restrict__ wpk,
    const float* __restrict__ bias,           // conv_b[256], o = g*64+j
    float* __restrict__ cbuf,                 // [b][625][64] fp32
    unsigned short* __restrict__ hbf,         // [b][m*64+j] relu'd bf16 h (t=TT-1)
    int t)
{
    __shared__ __align__(16) unsigned short at2[1620*8];   // [10 u][6r*27c][8], 25.92 KB

    const int tid  = threadIdx.x;
    const int mg   = blockIdx.x;              // 0..9 (64 m each; m 625..639 pad)
    const int b    = blockIdx.y;
    const int lane = tid & 63;
    const int nt   = tid >> 6;                // wave id = n-tile
    const int rlo  = (mg*64)/25;              // first output row of this m-group

    // ---- stage A-tile: rows rlo-1..rlo+4, cols -1..25, zero halo/pad ----
    const unsigned short* ib = inp + (size_t)b*IPB;
    for (int idx = tid; idx < 1620; idx += 512){
        int q   = idx/162, pix = idx - q*162;
        int rr  = pix/27,  cc  = pix - rr*27;
        int gr  = rlo - 1 + rr, gc = cc - 1;
        float4 v = {0.f,0.f,0.f,0.f};
        if ((unsigned)gr < 25u && (unsigned)gc < 25u)
            v = *reinterpret_cast<const float4*>(ib + (((size_t)q*PLANE + gr*25 + gc)<<3));
        *reinterpret_cast<float4*>(at2 + ((size_t)idx<<3)) = v;
    }

    // per-lane A bases for the wave's 2 m-tiles (rebased so all tap offsets >= 0)
    const int kh = lane >> 5;
    const unsigned short *a0, *a1;
    {
        int m0 = mg*64 + 0*32 + (lane & 31);
        int r_ = m0/25, c_ = m0 - r_*25;
        a0 = at2 + kh*1296 + (((r_ - rlo + 1)*27 + c_ - 27) << 3);
        int m1 = mg*64 + 1*32 + (lane & 31);
        r_ = m1/25; c_ = m1 - r_*25;
        a1 = at2 + kh*1296 + (((r_ - rlo + 1)*27 + c_ - 27) << 3);
    }

    f32x16 acc0, acc1;
    #pragma unroll
    for (int e = 0; e < 16; ++e){ acc0[e] = 0.f; acc1[e] = 0.f; }

    __syncthreads();

    // ---- K loop: 45 kb fully unrolled; A 3-deep, B 4-deep modulo rotation ----
    const bf16x8* wf = reinterpret_cast<const bf16x8*>(wpk) + nt*64 + lane;
    bf16x8 fa0[3], fa1[3], bb[4];
    #pragma unroll
    for (int i = 0; i < 3; ++i){
        fa0[i] = *reinterpret_cast<const bf16x8*>(a0 + AOFF(i));
        fa1[i] = *reinterpret_cast<const bf16x8*>(a1 + AOFF(i));
    }
    #pragma unroll
    for (int i = 0; i < 4; ++i) bb[i] = wf[i*512];

    #pragma unroll
    for (int kb = 0; kb < NKB; ++kb){
        acc0 = __builtin_amdgcn_mfma_f32_32x32x16_bf16(fa0[kb%3], bb[kb%4], acc0, 0,0,0);
        acc1 = __builtin_amdgcn_mfma_f32_32x32x16_bf16(fa1[kb%3], bb[kb%4], acc1, 0,0,0);
        if (kb + 3 < NKB){
            fa0[kb%3] = *reinterpret_cast<const bf16x8*>(a0 + AOFF(kb+3));
            fa1[kb%3] = *reinterpret_cast<const bf16x8*>(a1 + AOFF(kb+3));
        }
        if (kb + 4 < NKB) bb[kb%4] = wf[(kb+4)*512];
    }

    // ---- fused LSTM epilogue: quad transpose -> all lanes update ----
    const int g   = lane & 3;
    const int jlo = (lane & 31) >> 2;
    const int j   = nt*8 + jlo;
    const float bown = bias[g*64 + j];
    const float sA = (g == 3) ? 2.f : 1.f;    // act = sA*sigm(sA*x) + sB (tanh when g=3)
    const float sB = (g == 3) ? -1.f : 0.f;
    const int  mbase = mg*64 + 4*kh;
    const bool gb0 = (g & 1), gb1 = (g & 2);
    float* cb = cbuf + (size_t)b*PLANE*HID;
    unsigned short* hn  = inpn + (size_t)b*IPB;
    unsigned short* hfb = hbf  + (size_t)b*40000;
    const int chh = CIN + j, uh = chh >> 3, sh = chh & 7;

    #pragma unroll
    for (int mt = 0; mt < 2; ++mt){
        const f32x16& A = mt ? acc1 : acc0;
        #pragma unroll
        for (int rq = 0; rq < 4; ++rq){
            float v0 = fmaf(sA, fsigm(sA*(A[rq*4+0] + bown)), sB);
            float v1 = fmaf(sA, fsigm(sA*(A[rq*4+1] + bown)), sB);
            float v2 = fmaf(sA, fsigm(sA*(A[rq*4+2] + bown)), sB);
            float v3 = fmaf(sA, fsigm(sA*(A[rq*4+3] + bown)), sB);
            float s;
            s = __shfl_xor(gb0 ? v0 : v1, 1); if (gb0) v0 = s; else v1 = s;
            s = __shfl_xor(gb0 ? v2 : v3, 1); if (gb0) v2 = s; else v3 = s;
            s = __shfl_xor(gb1 ? v0 : v2, 2); if (gb1) v0 = s; else v2 = s;
            s = __shfl_xor(gb1 ? v1 : v3, 2); if (gb1) v1 = s; else v3 = s;
            // v0=i, v1=f, v2=o, v3=g~ of element m
            const int m = mbase + mt*32 + g + 8*rq;
            if (m < PLANE){
                float co = cb[m*HID + j];
                float cn = fmaf(v1, co, v0*v3);
                float h  = v2 * ftanh(cn);
                if (t < TT-1){
                    cb[m*HID + j] = cn;
                    hn[((uh*PLANE + m) << 3) + sh] = f2bf(h);
                } else {
                    hfb[m*64 + j] = f2bf(h > 0.f ? h : 0.f);
                }
            }
        }
    }

    // ---- fused x-copy for step t+1 (this block's 64-m slice) ----
    if (t < TT-1){
        const float* xn = x + (size_t)(b*TT + t + 1)*CIN*PLANE;
        for (int idx = tid; idx < 640; idx += 512){
            int ch = idx >> 6, mi = idx & 63;
            int m = mg*64 + mi;
            if (m < PLANE)
                inpn[(size_t)b*IPB + ((((ch>>3)*PLANE) + m)<<3) + (ch&7)] =
                    f2bf(xn[ch*PLANE + m]);
        }
    }
}

// -------- MLP stage 1: partial h@w1, coalesced bf16 h + transposed w1 --------
__global__ __launch_bounds__(256) void k_mlp1(
    const unsigned short* __restrict__ hbf, const float* __restrict__ w1t,
    float* __restrict__ part)
{
    __shared__ float xw[4][4][16];
    const int ks = blockIdx.x, bg = blockIdx.y, tid = threadIdx.x;
    const int kw0 = ks*4000, kw1 = kw0 + 4000;
    const unsigned short* h0 = hbf + (size_t)(bg*4+0)*40000;
    const unsigned short* h1 = hbf + (size_t)(bg*4+1)*40000;
    const unsigned short* h2 = hbf + (size_t)(bg*4+2)*40000;
    const unsigned short* h3 = hbf + (size_t)(bg*4+3)*40000;

    float acc[4][16];
    #pragma unroll
    for (int bi = 0; bi < 4; ++bi)
        #pragma unroll
        for (int n = 0; n < 16; ++n) acc[bi][n] = 0.f;

    for (int kw = kw0 + tid*2; kw < kw1; kw += 512){
        const float4* wp = (const float4*)(w1t + (size_t)kw*16);
        float4 q0 = wp[0], q1 = wp[1], q2 = wp[2], q3 = wp[3];
        float4 r0 = wp[4], r1 = wp[5], r2 = wp[6], r3 = wp[7];
        unsigned int u0 = *(const unsigned int*)(h0 + kw);
        unsigned int u1 = *(const unsigned int*)(h1 + kw);
        unsigned int u2 = *(const unsigned int*)(h2 + kw);
        unsigned int u3 = *(const unsigned int*)(h3 + kw);
        #define ACC1(bi, u) { \
            float fl = __uint_as_float((u) << 16); \
            float fh = __uint_as_float((u) & 0xffff0000u); \
            acc[bi][ 0]=fmaf(fl,q0.x,fmaf(fh,r0.x,acc[bi][ 0])); \
            acc[bi][ 1]=fmaf(fl,q0.y,fmaf(fh,r0.y,acc[bi][ 1])); \
            acc[bi][ 2]=fmaf(fl,q0.z,fmaf(fh,r0.z,acc[bi][ 2])); \
            acc[bi][ 3]=fmaf(fl,q0.w,fmaf(fh,r0.w,acc[bi][ 3])); \
            acc[bi][ 4]=fmaf(fl,q1.x,fmaf(fh,r1.x,acc[bi][ 4])); \
            acc[bi][ 5]=fmaf(fl,q1.y,fmaf(fh,r1.y,acc[bi][ 5])); \
            acc[bi][ 6]=fmaf(fl,q1.z,fmaf(fh,r1.z,acc[bi][ 6])); \
            acc[bi][ 7]=fmaf(fl,q1.w,fmaf(fh,r1.w,acc[bi][ 7])); \
            acc[bi][ 8]=fmaf(fl,q2.x,fmaf(fh,r2.x,acc[bi][ 8])); \
            acc[bi][ 9]=fmaf(fl,q2.y,fmaf(fh,r2.y,acc[bi][ 9])); \
            acc[bi][10]=fmaf(fl,q2.z,fmaf(fh,r2.z,acc[bi][10])); \
            acc[bi][11]=fmaf(fl,q2.w,fmaf(fh,r2.w,acc[bi][11])); \
            acc[bi][12]=fmaf(fl,q3.x,fmaf(fh,r3.x,acc[bi][12])); \
            acc[bi][13]=fmaf(fl,q3.y,fmaf(fh,r3.y,acc[bi][13])); \
            acc[bi][14]=fmaf(fl,q3.z,fmaf(fh,r3.z,acc[bi][14])); \
            acc[bi][15]=fmaf(fl,q3.w,fmaf(fh,r3.w,acc[bi][15])); }
        ACC1(0, u0) ACC1(1, u1) ACC1(2, u2) ACC1(3, u3)
        #undef ACC1
    }

    #pragma unroll
    for (int d = 1; d < 64; d <<= 1)
        #pragma unroll
        for (int bi = 0; bi < 4; ++bi)
            #pragma unroll
            for (int n = 0; n < 16; ++n) acc[bi][n] += __shfl_xor(acc[bi][n], d);
    if ((tid & 63) == 0){
        int w = tid >> 6;
        #pragma unroll
        for (int bi = 0; bi < 4; ++bi)
            #pragma unroll
            for (int n = 0; n < 16; ++n) xw[w][bi][n] = acc[bi][n];
    }
    __syncthreads();
    if (tid < 64){
        int bi = tid >> 4, n = tid & 15;
        float s = xw[0][bi][n] + xw[1][bi][n] + xw[2][bi][n] + xw[3][bi][n];
        part[((size_t)(bg*4 + bi)*KSPLIT + ks)*16 + n] = s;
    }
}

// -------- MLP stage 2: fold partials, 16 -> 8 -> 2 -> log_softmax --------
__global__ __launch_bounds__(128) void k_mlp2(
    const float* __restrict__ part,
    const float* __restrict__ b1,
    const float* __restrict__ w2, const float* __restrict__ b2,
    const float* __restrict__ w3, const float* __restrict__ b3,
    float* __restrict__ out)
{
    const int b = threadIdx.x;
    float h1[16];
    #pragma unroll
    for (int i = 0; i < 16; ++i) h1[i] = b1[i];
    for (int s = 0; s < KSPLIT; ++s)
        #pragma unroll
        for (int i = 0; i < 16; ++i) h1[i] += part[((size_t)b * KSPLIT + s) * 16 + i];
    #pragma unroll
    for (int i = 0; i < 16; ++i) h1[i] = h1[i] > 0.f ? h1[i] : 0.f;

    float h2[8];
    #pragma unroll
    for (int i = 0; i < 8; ++i){
        float s2 = b2[i];
        #pragma unroll
        for (int k2 = 0; k2 < 16; ++k2) s2 += h1[k2] * w2[k2*8 + i];
        h2[i] = s2 > 0.f ? s2 : 0.f;
    }
    float l0 = b3[0], l1 = b3[1];
    #pragma unroll
    for (int k3 = 0; k3 < 8; ++k3){ l0 += h2[k3]*w3[k3*2]; l1 += h2[k3]*w3[k3*2+1]; }
    float m   = fmaxf(l0, l1);
    float lse = m + logf(__expf(l0 - m) + __expf(l1 - m));
    out[b*2 + 0] = l0 - lse;
    out[b*2 + 1] = l1 - lse;
}

extern "C" void kernel_launch(void* const* d_in, const int* in_sizes, int n_in,
                              void* d_out, int out_size, void* d_ws, size_t ws_size,
                              hipStream_t stream) {
    const float* x      = (const float*)d_in[0];
    const float* conv_w = (const float*)d_in[1];
    const float* conv_b = (const float*)d_in[2];
    const float* w1     = (const float*)d_in[3];
    const float* b1     = (const float*)d_in[4];
    const float* w2     = (const float*)d_in[5];
    const float* b2     = (const float*)d_in[6];
    const float* w3     = (const float*)d_in[7];
    const float* b3     = (const float*)d_in[8];
    float* out = (float*)d_out;

    unsigned short* inp0 = (unsigned short*)d_ws;
    unsigned short* inp1 = inp0 + (size_t)BATCH*IPB;
    float* c   = (float*)(inp1 + (size_t)BATCH*IPB);
    unsigned short* hbf = (unsigned short*)(c + CSZ);
    unsigned short* wpk = hbf + (size_t)BATCH*40000;
    float* w1t  = (float*)(wpk + (size_t)NKB_ALLOC*8*64*8);
    float* part = w1t + 640000;

    // ws poisoned 0xAA, not re-poisoned between replays -> re-init every call
    hipMemsetAsync(inp0, 0, (size_t)BATCH*IPB*2, stream);   // zeros h(t=0) + ch pad
    hipMemsetAsync(inp1, 0, (size_t)BATCH*IPB*2, stream);   // zeros ch pad
    hipMemsetAsync(c,    0, (size_t)CSZ*4,       stream);

    k_wprep <<<dim3(90),   dim3(256), 0, stream>>>(conv_w, wpk);
    k_w1prep<<<dim3(625),  dim3(256), 0, stream>>>(w1, w1t);
    k_xcopy <<<dim3(3125), dim3(256), 0, stream>>>(x, inp0, 0);

    for (int t = 0; t < TT; ++t){
        unsigned short* ic  = (t & 1) ? inp1 : inp0;
        unsigned short* in_ = (t & 1) ? inp0 : inp1;
        k_gemm<<<dim3(10, BATCH), dim3(512), 0, stream>>>(x, ic, in_, wpk, conv_b, c, hbf, t);
    }
    k_mlp1<<<dim3(KSPLIT, 32), dim3(256), 0, stream>>>(hbf, w1t, part);
    k_mlp2<<<dim3(1), dim3(128), 0, stream>>>(part, b1, w2, b2, w3, b3, out);
}